// Round 1
// baseline (5539.356 us; speedup 1.0000x reference)
//
#include <hip/hip_runtime.h>

// ----------------------------------------------------------------------------
// Luna cross-attention block, fp32 in/out.
// GEMMs run as bf16x3 split-precision MFMA (hi/lo split; 3 mfma per K-step)
// => ~fp32 accuracy on the matrix pipe. Attention is fp32 vector flash-style.
//
// Workspace layout (floats), total 37,748,736 floats = 151 MB:
//   W0 = ws + 0          (16M)  Kx -> Qx -> x_att -> mlp hidden (per pass)
//   W1 = ws + 16777216   (16M)  Vx -> attn2 out -> x_ff (accumulated)
//   S0 = ws + 33554432   (1M)   Qp -> Kp
//   S1 = S0 + 1M                attn1 out
//   S2 = S1 + 1M                p_att
//   S3 = S2 + 1M                Vp
// x1 (post-attention layernormed x) is staged in d_out[0:16M] and consumed /
// overwritten in place by the final layernorm.
// ----------------------------------------------------------------------------

typedef short bf16x8 __attribute__((ext_vector_type(8)));
typedef float f32x4 __attribute__((ext_vector_type(4)));
typedef unsigned short us4 __attribute__((ext_vector_type(4)));

__device__ __forceinline__ unsigned short f2bf(float f) {
  unsigned u = __float_as_uint(f);
  u += 0x7FFFu + ((u >> 16) & 1u);   // round-to-nearest-even
  return (unsigned short)(u >> 16);
}
__device__ __forceinline__ float bf2f(unsigned short h) {
  return __uint_as_float(((unsigned)h) << 16);
}

// ---------------------------------------------------------------- GEMM ------
// C[M,N] = A[M,K] @ B[K,N] (+bias) (gelu) (+=C). Row-major, lda/ldb/ldc.
// Tile 128x128, BK=32, 4 waves (2x2), each wave 64x64 = 4x4 fragments of
// 16x16x32 bf16 MFMA. A/B staged fp32->bf16(hi,lo) each K-step.
// flags: 1=bias, 2=gelu(exact), 4=accumulate into C.
#define GLD 56  // LDS row stride in shorts: 112B, 16B-aligned, ~2-way banks

__global__ __launch_bounds__(256) void gemm_kernel(
    const float* __restrict__ A, int lda,
    const float* __restrict__ Bw, int ldb,
    const float* __restrict__ bias,
    float* __restrict__ C, int ldc,
    int K, int flags)
{
  __shared__ unsigned short Ah[128 * GLD];
  __shared__ unsigned short Al[128 * GLD];
  __shared__ unsigned short Bh[128 * GLD];
  __shared__ unsigned short Bl[128 * GLD];

  const int tid  = threadIdx.x;
  const int brow = blockIdx.y * 128;
  const int bcol = blockIdx.x * 128;
  const int lane = tid & 63;
  const int w    = tid >> 6;
  const int wr   = (w >> 1) * 64;       // wave row offset in tile
  const int wc   = (w & 1) * 64;        // wave col offset in tile
  const int ti   = lane & 15;
  const int kg   = (lane >> 4) * 8;     // k-slot group (permutation cancels A/B)

  const f32x4 zero4 = {0.f, 0.f, 0.f, 0.f};
  f32x4 acc[4][4];
#pragma unroll
  for (int m = 0; m < 4; m++)
#pragma unroll
    for (int n = 0; n < 4; n++) acc[m][n] = zero4;

  for (int kb = 0; kb < K; kb += 32) {
    __syncthreads();
    // stage A tile: 128 rows x 32 cols fp32 -> hi/lo bf16
#pragma unroll
    for (int q = 0; q < 4; q++) {
      int s   = tid + q * 256;          // 0..1023
      int row = s >> 3;
      int c4  = (s & 7) * 4;
      float4 f = *(const float4*)(A + (size_t)(brow + row) * lda + kb + c4);
      unsigned short hx = f2bf(f.x), hy = f2bf(f.y), hz = f2bf(f.z), hw = f2bf(f.w);
      us4 hi = {hx, hy, hz, hw};
      us4 lo = {f2bf(f.x - bf2f(hx)), f2bf(f.y - bf2f(hy)),
                f2bf(f.z - bf2f(hz)), f2bf(f.w - bf2f(hw))};
      *(us4*)&Ah[row * GLD + c4] = hi;
      *(us4*)&Al[row * GLD + c4] = lo;
    }
    // stage B tile: 32 rows x 128 cols fp32 -> hi/lo bf16, TRANSPOSED (Bt[col][k])
#pragma unroll
    for (int q = 0; q < 4; q++) {
      int s  = tid + q * 256;
      int kr = s >> 5;                  // 0..31
      int c4 = (s & 31) * 4;            // 0..124
      float4 f = *(const float4*)(Bw + (size_t)(kb + kr) * ldb + bcol + c4);
      unsigned short h0 = f2bf(f.x);
      Bh[(c4 + 0) * GLD + kr] = h0; Bl[(c4 + 0) * GLD + kr] = f2bf(f.x - bf2f(h0));
      unsigned short h1 = f2bf(f.y);
      Bh[(c4 + 1) * GLD + kr] = h1; Bl[(c4 + 1) * GLD + kr] = f2bf(f.y - bf2f(h1));
      unsigned short h2 = f2bf(f.z);
      Bh[(c4 + 2) * GLD + kr] = h2; Bl[(c4 + 2) * GLD + kr] = f2bf(f.z - bf2f(h2));
      unsigned short h3 = f2bf(f.w);
      Bh[(c4 + 3) * GLD + kr] = h3; Bl[(c4 + 3) * GLD + kr] = f2bf(f.w - bf2f(h3));
    }
    __syncthreads();

    bf16x8 ah[4], al[4], bh[4], bl[4];
#pragma unroll
    for (int m = 0; m < 4; m++) {
      int off = (wr + m * 16 + ti) * GLD + kg;
      ah[m] = *(const bf16x8*)&Ah[off];
      al[m] = *(const bf16x8*)&Al[off];
    }
#pragma unroll
    for (int n = 0; n < 4; n++) {
      int off = (wc + n * 16 + ti) * GLD + kg;
      bh[n] = *(const bf16x8*)&Bh[off];
      bl[n] = *(const bf16x8*)&Bl[off];
    }
#pragma unroll
    for (int m = 0; m < 4; m++)
#pragma unroll
      for (int n = 0; n < 4; n++) {
        acc[m][n] = __builtin_amdgcn_mfma_f32_16x16x32_bf16(ah[m], bh[n], acc[m][n], 0, 0, 0);
        acc[m][n] = __builtin_amdgcn_mfma_f32_16x16x32_bf16(al[m], bh[n], acc[m][n], 0, 0, 0);
        acc[m][n] = __builtin_amdgcn_mfma_f32_16x16x32_bf16(ah[m], bl[n], acc[m][n], 0, 0, 0);
      }
  }

  // epilogue: C/D layout col=lane&15, row=(lane>>4)*4+j  [m89-verified]
  const int rg = (lane >> 4) * 4;
#pragma unroll
  for (int n = 0; n < 4; n++) {
    int col = bcol + wc + n * 16 + ti;
    float bv = (flags & 1) ? bias[col] : 0.0f;
#pragma unroll
    for (int m = 0; m < 4; m++) {
#pragma unroll
      for (int j = 0; j < 4; j++) {
        int row = brow + wr + m * 16 + rg + j;
        float v = acc[m][n][j] + bv;
        if (flags & 2) v = 0.5f * v * (1.0f + erff(v * 0.70710678118654752f));
        size_t off = (size_t)row * ldc + col;
        if (flags & 4) v += C[off];
        C[off] = v;
      }
    }
  }
}

// ------------------------------------------------------------- attention ----
// Flash-style. Layouts (B, N, H*64) row-major, stride 1024. One block per
// (b, h, 64-query tile); streams 64-key tiles with online softmax.
// Threads: 16x16; thread (ti,tj) owns S/P rows ti*4..+4 x cols tj*4..+4 and
// O rows ti*4..+4 x d-cols tj*4..+4. P is written into the (dead) K-tile LDS.
#define ALD 68

__global__ __launch_bounds__(256) void attn_kernel(
    const float* __restrict__ Q, const float* __restrict__ K,
    const float* __restrict__ V, float* __restrict__ O,
    int Nq, int Nk)
{
  __shared__ float Qs[64 * ALD];
  __shared__ float Ks[64 * ALD];   // K tile, then reused for P
  __shared__ float Vs[64 * ALD];

  const int tid = threadIdx.x;
  const int nqt = Nq >> 6;
  const int qt  = blockIdx.x % nqt;
  const int h   = (blockIdx.x / nqt) & 15;
  const int b   = blockIdx.x / (nqt * 16);

  const float* Qb = Q + ((size_t)b * Nq + qt * 64) * 1024 + h * 64;
  const float* Kb = K + (size_t)b * Nk * 1024 + h * 64;
  const float* Vb = V + (size_t)b * Nk * 1024 + h * 64;

#pragma unroll
  for (int q = 0; q < 4; q++) {
    int s = tid + q * 256;
    int i = s >> 4, d4 = (s & 15) * 4;
    float4 f = *(const float4*)(Qb + (size_t)i * 1024 + d4);
    Qs[i * ALD + d4 + 0] = f.x * 0.125f;   // fold in SCALE = 1/sqrt(64)
    Qs[i * ALD + d4 + 1] = f.y * 0.125f;
    Qs[i * ALD + d4 + 2] = f.z * 0.125f;
    Qs[i * ALD + d4 + 3] = f.w * 0.125f;
  }

  const int ti = tid >> 4, tj = tid & 15;
  const int i0 = ti * 4, j0 = tj * 4;
  float m_r[4] = {-1e30f, -1e30f, -1e30f, -1e30f};
  float l_r[4] = {0.f, 0.f, 0.f, 0.f};
  float o[4][4] = {};

  for (int kt = 0; kt < Nk; kt += 64) {
    __syncthreads();   // previous iteration's PV fully done
#pragma unroll
    for (int q = 0; q < 4; q++) {
      int s = tid + q * 256;
      int j = s >> 4, d4 = (s & 15) * 4;
      float4 f = *(const float4*)(Kb + (size_t)(kt + j) * 1024 + d4);
      Ks[j * ALD + d4 + 0] = f.x; Ks[j * ALD + d4 + 1] = f.y;
      Ks[j * ALD + d4 + 2] = f.z; Ks[j * ALD + d4 + 3] = f.w;
      float4 g = *(const float4*)(Vb + (size_t)(kt + j) * 1024 + d4);
      Vs[j * ALD + d4 + 0] = g.x; Vs[j * ALD + d4 + 1] = g.y;
      Vs[j * ALD + d4 + 2] = g.z; Vs[j * ALD + d4 + 3] = g.w;
    }
    __syncthreads();

    // S = (Q*scale) . K^T, 4x4 per thread
    float s4[4][4] = {};
    for (int k = 0; k < 64; k += 4) {
      float4 qv[4], kv[4];
#pragma unroll
      for (int r = 0; r < 4; r++) qv[r] = *(const float4*)&Qs[(i0 + r) * ALD + k];
#pragma unroll
      for (int c = 0; c < 4; c++) kv[c] = *(const float4*)&Ks[(j0 + c) * ALD + k];
#pragma unroll
      for (int r = 0; r < 4; r++)
#pragma unroll
        for (int c = 0; c < 4; c++)
          s4[r][c] += qv[r].x * kv[c].x + qv[r].y * kv[c].y +
                      qv[r].z * kv[c].z + qv[r].w * kv[c].w;
    }

    // online softmax; row groups are 16 consecutive lanes (shfl_xor 1/2/4/8)
    float alpha[4], p[4][4];
#pragma unroll
    for (int r = 0; r < 4; r++) {
      float mx = fmaxf(fmaxf(s4[r][0], s4[r][1]), fmaxf(s4[r][2], s4[r][3]));
      mx = fmaxf(mx, __shfl_xor(mx, 1));
      mx = fmaxf(mx, __shfl_xor(mx, 2));
      mx = fmaxf(mx, __shfl_xor(mx, 4));
      mx = fmaxf(mx, __shfl_xor(mx, 8));
      float mn = fmaxf(m_r[r], mx);
      float rs = 0.f;
#pragma unroll
      for (int c = 0; c < 4; c++) { p[r][c] = __expf(s4[r][c] - mn); rs += p[r][c]; }
      rs += __shfl_xor(rs, 1);
      rs += __shfl_xor(rs, 2);
      rs += __shfl_xor(rs, 4);
      rs += __shfl_xor(rs, 8);
      alpha[r] = __expf(m_r[r] - mn);
      l_r[r] = l_r[r] * alpha[r] + rs;
      m_r[r] = mn;
    }

    __syncthreads();   // everyone done reading K tile
#pragma unroll
    for (int r = 0; r < 4; r++) {
      float4 t = make_float4(p[r][0], p[r][1], p[r][2], p[r][3]);
      *(float4*)&Ks[(i0 + r) * ALD + j0] = t;   // P into dead K-tile LDS
    }
    __syncthreads();

#pragma unroll
    for (int r = 0; r < 4; r++)
#pragma unroll
      for (int d = 0; d < 4; d++) o[r][d] *= alpha[r];

    // O += P @ V
    for (int j = 0; j < 64; j += 4) {
      float4 pv[4], vv[4];
#pragma unroll
      for (int r = 0; r < 4; r++) pv[r] = *(const float4*)&Ks[(i0 + r) * ALD + j];
#pragma unroll
      for (int c = 0; c < 4; c++) vv[c] = *(const float4*)&Vs[(j + c) * ALD + j0];
#pragma unroll
      for (int r = 0; r < 4; r++) {
        o[r][0] += pv[r].x * vv[0].x + pv[r].y * vv[1].x + pv[r].z * vv[2].x + pv[r].w * vv[3].x;
        o[r][1] += pv[r].x * vv[0].y + pv[r].y * vv[1].y + pv[r].z * vv[2].y + pv[r].w * vv[3].y;
        o[r][2] += pv[r].x * vv[0].z + pv[r].y * vv[1].z + pv[r].z * vv[2].z + pv[r].w * vv[3].z;
        o[r][3] += pv[r].x * vv[0].w + pv[r].y * vv[1].w + pv[r].z * vv[2].w + pv[r].w * vv[3].w;
      }
    }
  }

#pragma unroll
  for (int r = 0; r < 4; r++) {
    float inv = 1.0f / l_r[r];
    float4 t = make_float4(o[r][0] * inv, o[r][1] * inv, o[r][2] * inv, o[r][3] * inv);
    *(float4*)(O + ((size_t)b * Nq + qt * 64 + i0 + r) * 1024 + h * 64 + j0) = t;
  }
}

// -------------------------------------------------------------- add + LN ----
// out[row] = LN(A[row] + R[row]) * g + b ; row length fixed 1024, one block/row
__global__ __launch_bounds__(256) void add_ln_kernel(
    const float* __restrict__ A, const float* __restrict__ R,
    const float* __restrict__ g, const float* __restrict__ be,
    float* __restrict__ out)
{
  const int row = blockIdx.x;
  const size_t base = (size_t)row * 1024 + threadIdx.x * 4;
  float4 a = *(const float4*)(A + base);
  float4 r = *(const float4*)(R + base);
  float v0 = a.x + r.x, v1 = a.y + r.y, v2 = a.z + r.z, v3 = a.w + r.w;
  float s  = v0 + v1 + v2 + v3;
  float ss = v0 * v0 + v1 * v1 + v2 * v2 + v3 * v3;
#pragma unroll
  for (int m = 1; m < 64; m <<= 1) { s += __shfl_xor(s, m); ss += __shfl_xor(ss, m); }
  __shared__ float red[8];
  const int wid = threadIdx.x >> 6;
  if ((threadIdx.x & 63) == 0) { red[wid] = s; red[4 + wid] = ss; }
  __syncthreads();
  s  = red[0] + red[1] + red[2] + red[3];
  ss = red[4] + red[5] + red[6] + red[7];
  float mean = s * (1.0f / 1024.0f);
  float var  = ss * (1.0f / 1024.0f) - mean * mean;
  float inv  = 1.0f / sqrtf(var + 1e-5f);
  float4 gg = *(const float4*)(g + threadIdx.x * 4);
  float4 bb = *(const float4*)(be + threadIdx.x * 4);
  float4 ov;
  ov.x = (v0 - mean) * inv * gg.x + bb.x;
  ov.y = (v1 - mean) * inv * gg.y + bb.y;
  ov.z = (v2 - mean) * inv * gg.z + bb.z;
  ov.w = (v3 - mean) * inv * gg.w + bb.w;
  *(float4*)(out + base) = ov;
}

// ---------------------------------------------------------------- launch ----
extern "C" void kernel_launch(void* const* d_in, const int* in_sizes, int n_in,
                              void* d_out, int out_size, void* d_ws, size_t ws_size,
                              hipStream_t stream)
{
  const float* x    = (const float*)d_in[0];
  const float* p    = (const float*)d_in[1];
  const float* pq_w = (const float*)d_in[2];
  const float* pk_w = (const float*)d_in[3];
  const float* pv_w = (const float*)d_in[4];
  const float* po_w = (const float*)d_in[5];
  const float* po_b = (const float*)d_in[6];
  const float* xq_w = (const float*)d_in[7];
  const float* xk_w = (const float*)d_in[8];
  const float* xv_w = (const float*)d_in[9];
  const float* xo_w = (const float*)d_in[10];
  const float* xo_b = (const float*)d_in[11];
  const float* pn_g = (const float*)d_in[12];
  const float* pn_b = (const float*)d_in[13];
  const float* xn_g = (const float*)d_in[14];
  const float* xn_b = (const float*)d_in[15];
  const float* w1   = (const float*)d_in[16];
  const float* b1   = (const float*)d_in[17];
  const float* w2   = (const float*)d_in[18];
  const float* b2   = (const float*)d_in[19];
  const float* fn_g = (const float*)d_in[20];
  const float* fn_b = (const float*)d_in[21];

  float* out_x = (float*)d_out;            // (4,4096,1024)
  float* out_p = out_x + 16777216;         // (4,256,1024)

  float* ws = (float*)d_ws;
  float* W0 = ws;                          // 16M floats
  float* W1 = ws + 16777216;               // 16M floats
  float* S0 = ws + 33554432;               // 1M floats
  float* S1 = S0 + 1048576;
  float* S2 = S1 + 1048576;
  float* S3 = S2 + 1048576;

  const dim3 blk(256, 1, 1);
#define GEMM(A_, lda_, B_, ldb_, bias_, C_, ldc_, M_, N_, K_, fl_)              \
  gemm_kernel<<<dim3((N_) / 128, (M_) / 128, 1), blk, 0, stream>>>(             \
      A_, lda_, B_, ldb_, bias_, C_, ldc_, K_, fl_)

  // ---- p attends to x ----
  GEMM(p, 1024, pq_w, 1024, nullptr, S0, 1024, 1024, 1024, 1024, 0);    // Qp
  GEMM(x, 1024, pk_w, 1024, nullptr, W0, 1024, 16384, 1024, 1024, 0);   // Kx
  GEMM(x, 1024, pv_w, 1024, nullptr, W1, 1024, 16384, 1024, 1024, 0);   // Vx
  attn_kernel<<<dim3(4 * 16 * (256 / 64)), blk, 0, stream>>>(S0, W0, W1, S1, 256, 4096);
  GEMM(S1, 1024, po_w, 1024, po_b, S2, 1024, 1024, 1024, 1024, 1);      // p_att
  add_ln_kernel<<<dim3(1024), blk, 0, stream>>>(S2, p, pn_g, pn_b, out_p);  // p_new

  // ---- x attends to p_att ----
  GEMM(x, 1024, xq_w, 1024, nullptr, W0, 1024, 16384, 1024, 1024, 0);   // Qx
  GEMM(S2, 1024, xk_w, 1024, nullptr, S0, 1024, 1024, 1024, 1024, 0);   // Kp
  GEMM(S2, 1024, xv_w, 1024, nullptr, S3, 1024, 1024, 1024, 1024, 0);   // Vp
  attn_kernel<<<dim3(4 * 16 * (4096 / 64)), blk, 0, stream>>>(W0, S0, S3, W1, 4096, 256);
  GEMM(W1, 1024, xo_w, 1024, xo_b, W0, 1024, 16384, 1024, 1024, 1);     // x_att
  add_ln_kernel<<<dim3(16384), blk, 0, stream>>>(W0, x, xn_g, xn_b, out_x);  // x1

  // ---- MLP, split along hidden dim into 4 passes of 1024 ----
  for (int nt = 0; nt < 4; nt++) {
    GEMM(out_x, 1024, w1 + nt * 1024, 4096, b1 + nt * 1024, W0, 1024,
         16384, 1024, 1024, 1 | 2);                                      // gelu(x1@w1+b1)
    GEMM(W0, 1024, w2 + (size_t)nt * 1024 * 1024, 1024,
         (nt == 0) ? b2 : nullptr, W1, 1024, 16384, 1024, 1024,
         (nt == 0) ? 1 : 4);                                             // x_ff (+=)
  }
  add_ln_kernel<<<dim3(16384), blk, 0, stream>>>(W1, out_x, fn_g, fn_b, out_x);
#undef GEMM
}

// Round 6
// 2856.003 us; speedup vs baseline: 1.9395x; 1.9395x over previous
//
#include <hip/hip_runtime.h>

// ----------------------------------------------------------------------------
// Luna cross-attention block, fp32 in/out.
// GEMMs: bf16x3 split-precision MFMA (hi/lo split; 3 mfma per K-step).
// fp32->bf16 via v_cvt_pk_bf16_f32. B is staged k-major in LDS (same layout
// family as A) via in-register v_perm k-packing + vector ds_write_b64; both
// operands' fragments are plain ds_read_b64 with IDENTICAL k-slot maps
// (kappa(g,j) = {4g+j, 16+4g+j}), so the slot permutation cancels in MFMA
// (property empirically proven by round-1's passing kernel).
// Attention: fp32 vector flash-style with XOR-swizzled LDS (conflict-free).
//
// Workspace layout (floats), total 37,748,736 floats = 151 MB (r1-proven).
// ----------------------------------------------------------------------------

typedef short bf16x8 __attribute__((ext_vector_type(8)));
typedef float f32x4 __attribute__((ext_vector_type(4)));
typedef unsigned int u32x2 __attribute__((ext_vector_type(2)));
typedef unsigned int u32x4v __attribute__((ext_vector_type(4)));

__device__ __forceinline__ unsigned cvt_pk_bf16(float a, float b) {
  unsigned r;
  asm("v_cvt_pk_bf16_f32 %0, %1, %2" : "=v"(r) : "v"(a), "v"(b));
  return r;   // low 16 = bf16(a), high 16 = bf16(b)
}
__device__ __forceinline__ bf16x8 mk8(u32x2 a, u32x2 b) {
  u32x4v t; t.x = a.x; t.y = a.y; t.z = b.x; t.w = b.y;
  return __builtin_bit_cast(bf16x8, t);
}

// ---------------------------------------------------------------- GEMM ------
// C[M,N] = A[M,K] @ B[K,N] (+bias) (gelu) (+=C). Row-major inputs.
// Tile 128x128, BK=32, 4 waves (2x2), each wave 64x64 = 4x4 frags of
// 16x16x32 bf16 MFMA, 3 mfma per frag (AhBh + AlBh + AhBl).
// A LDS: Ah/Al [128 rows][AST=36] bf16, elem (row,k) at row*36+k.
// B LDS: Bh/Bl [128 n-rows][AST=36] bf16 k-major with per-row rotation:
//        elem (n,k) at n*36 + ((k + 4*((n>>2)&7)) & 31)   (write-conflict fix;
//        rotation is 4-aligned so b64 reads stay contiguous & 8B-aligned).
// flags: 1=bias, 2=gelu(exact), 4=accumulate into C.
#define AST 36
#define SEL_LO 0x05040100u
#define SEL_HI 0x07060302u

__global__ __launch_bounds__(256, 2) void gemm_kernel(
    const float* __restrict__ A, int lda,
    const float* __restrict__ Bw, int ldb,
    const float* __restrict__ bias,
    float* __restrict__ C, int ldc,
    int K, int flags)
{
  __shared__ __align__(16) unsigned short Ah[128 * AST];
  __shared__ __align__(16) unsigned short Al[128 * AST];
  __shared__ __align__(16) unsigned short Bh[128 * AST];
  __shared__ __align__(16) unsigned short Bl[128 * AST];

  const int tid = threadIdx.x;
  // m204 bijective XCD chunking (all grids here have nwg % 8 == 0)
  const int bid   = blockIdx.y * gridDim.x + blockIdx.x;
  const int chunk = (gridDim.x * gridDim.y) >> 3;
  const int lg    = (bid & 7) * chunk + (bid >> 3);
  const int bcol  = (lg % gridDim.x) * 128;
  const int brow  = (lg / gridDim.x) * 128;

  const int lane = tid & 63;
  const int w    = tid >> 6;
  const int wr   = (w >> 1) * 64;
  const int wc   = (w & 1) * 64;
  const int ti   = lane & 15;
  const int g    = lane >> 4;

  // global-load / staging maps (thread-constant)
  const int arow = tid >> 3;            // + 32q
  const int ac4  = (tid & 7) * 4;
  const int K0   = (tid >> 5) * 4;      // B k-row base; +q
  const int n4   = (tid & 31) * 4;      // B col base
  int bwa[4];                            // B LDS write element offsets
#pragma unroll
  for (int i = 0; i < 4; i++)
    bwa[i] = (n4 + i) * AST + ((K0 + 4 * (((n4 + i) >> 2) & 7)) & 31);
  int brofs[4], brbase[4];               // B frag read: row base + rotated off
#pragma unroll
  for (int nb = 0; nb < 4; nb++) {
    int n = wc + nb * 16 + ti;
    brbase[nb] = n * AST;
    brofs[nb]  = (4 * g + 4 * ((n >> 2) & 7)) & 31;
  }

  f32x4 acc[4][4];
#pragma unroll
  for (int m = 0; m < 4; m++)
#pragma unroll
    for (int n = 0; n < 4; n++) acc[m][n] = (f32x4){0.f, 0.f, 0.f, 0.f};

  float4 fA[4], fB[4];
#pragma unroll
  for (int q = 0; q < 4; q++) {
    fA[q] = *(const float4*)(A + (size_t)(brow + arow + 32 * q) * lda + ac4);
    fB[q] = *(const float4*)(Bw + (size_t)(K0 + q) * ldb + bcol + n4);
  }

  for (int kb = 0; kb < K; kb += 32) {
    __syncthreads();   // previous step's frag reads complete
    // ---- stage A (natural k-minor layout) ----
#pragma unroll
    for (int q = 0; q < 4; q++) {
      float4 f = fA[q];
      unsigned h01 = cvt_pk_bf16(f.x, f.y);
      unsigned h23 = cvt_pk_bf16(f.z, f.w);
      unsigned l01 = cvt_pk_bf16(f.x - __uint_as_float(h01 << 16),
                                 f.y - __uint_as_float(h01 & 0xffff0000u));
      unsigned l23 = cvt_pk_bf16(f.z - __uint_as_float(h23 << 16),
                                 f.w - __uint_as_float(h23 & 0xffff0000u));
      int el = (arow + 32 * q) * AST + ac4;
      *(uint2*)&Ah[el] = make_uint2(h01, h23);
      *(uint2*)&Al[el] = make_uint2(l01, l23);
    }
    // ---- stage B: convert 4x4 (k x n) block, k-pack via v_perm, b64 writes --
    {
      unsigned h01[4], h23[4], l01[4], l23[4];
#pragma unroll
      for (int q = 0; q < 4; q++) {
        float4 f = fB[q];
        h01[q] = cvt_pk_bf16(f.x, f.y);
        h23[q] = cvt_pk_bf16(f.z, f.w);
        l01[q] = cvt_pk_bf16(f.x - __uint_as_float(h01[q] << 16),
                             f.y - __uint_as_float(h01[q] & 0xffff0000u));
        l23[q] = cvt_pk_bf16(f.z - __uint_as_float(h23[q] << 16),
                             f.w - __uint_as_float(h23[q] & 0xffff0000u));
      }
      uint2 vh[4], vl[4];
      vh[0] = make_uint2(__builtin_amdgcn_perm(h01[1], h01[0], SEL_LO),
                         __builtin_amdgcn_perm(h01[3], h01[2], SEL_LO));
      vh[1] = make_uint2(__builtin_amdgcn_perm(h01[1], h01[0], SEL_HI),
                         __builtin_amdgcn_perm(h01[3], h01[2], SEL_HI));
      vh[2] = make_uint2(__builtin_amdgcn_perm(h23[1], h23[0], SEL_LO),
                         __builtin_amdgcn_perm(h23[3], h23[2], SEL_LO));
      vh[3] = make_uint2(__builtin_amdgcn_perm(h23[1], h23[0], SEL_HI),
                         __builtin_amdgcn_perm(h23[3], h23[2], SEL_HI));
      vl[0] = make_uint2(__builtin_amdgcn_perm(l01[1], l01[0], SEL_LO),
                         __builtin_amdgcn_perm(l01[3], l01[2], SEL_LO));
      vl[1] = make_uint2(__builtin_amdgcn_perm(l01[1], l01[0], SEL_HI),
                         __builtin_amdgcn_perm(l01[3], l01[2], SEL_HI));
      vl[2] = make_uint2(__builtin_amdgcn_perm(l23[1], l23[0], SEL_LO),
                         __builtin_amdgcn_perm(l23[3], l23[2], SEL_LO));
      vl[3] = make_uint2(__builtin_amdgcn_perm(l23[1], l23[0], SEL_HI),
                         __builtin_amdgcn_perm(l23[3], l23[2], SEL_HI));
#pragma unroll
      for (int i = 0; i < 4; i++) {
        *(uint2*)&Bh[bwa[i]] = vh[i];
        *(uint2*)&Bl[bwa[i]] = vl[i];
      }
    }
    __syncthreads();

    // ---- prefetch next K-step's globals (overlaps frag reads + MFMA) ----
    if (kb + 32 < K) {
#pragma unroll
      for (int q = 0; q < 4; q++) {
        fA[q] = *(const float4*)(A + (size_t)(brow + arow + 32 * q) * lda + kb + 32 + ac4);
        fB[q] = *(const float4*)(Bw + (size_t)(kb + 32 + K0 + q) * ldb + bcol + n4);
      }
    }

    // ---- fragment reads; slots j<4 -> k=4g+j, j>=4 -> k=16+4g+(j-4) on BOTH
    //      operands -> permutation cancels in the MFMA contraction. ----
    u32x2 fa_h[4][2], fa_l[4][2], fb_h[4][2], fb_l[4][2];
#pragma unroll
    for (int m = 0; m < 4; m++) {
      int e0 = (wr + m * 16 + ti) * AST + 4 * g;
      fa_h[m][0] = *(const u32x2*)&Ah[e0];
      fa_h[m][1] = *(const u32x2*)&Ah[e0 + 16];
      fa_l[m][0] = *(const u32x2*)&Al[e0];
      fa_l[m][1] = *(const u32x2*)&Al[e0 + 16];
    }
#pragma unroll
    for (int nb = 0; nb < 4; nb++) {
      int e0 = brbase[nb] + brofs[nb];
      int e1 = brbase[nb] + (brofs[nb] ^ 16);   // (off+16)&31 == off^16 (4-aligned)
      fb_h[nb][0] = *(const u32x2*)&Bh[e0];
      fb_h[nb][1] = *(const u32x2*)&Bh[e1];
      fb_l[nb][0] = *(const u32x2*)&Bl[e0];
      fb_l[nb][1] = *(const u32x2*)&Bl[e1];
    }

#pragma unroll
    for (int m = 0; m < 4; m++) {
      bf16x8 ah = mk8(fa_h[m][0], fa_h[m][1]);
      bf16x8 al = mk8(fa_l[m][0], fa_l[m][1]);
#pragma unroll
      for (int n = 0; n < 4; n++) {
        bf16x8 bh = mk8(fb_h[n][0], fb_h[n][1]);
        bf16x8 bl = mk8(fb_l[n][0], fb_l[n][1]);
        acc[m][n] = __builtin_amdgcn_mfma_f32_16x16x32_bf16(ah, bh, acc[m][n], 0, 0, 0);
        acc[m][n] = __builtin_amdgcn_mfma_f32_16x16x32_bf16(al, bh, acc[m][n], 0, 0, 0);
        acc[m][n] = __builtin_amdgcn_mfma_f32_16x16x32_bf16(ah, bl, acc[m][n], 0, 0, 0);
      }
    }
  }

  // epilogue: C/D layout col=lane&15, row=(lane>>4)*4+j  [m89-verified, r1-proven]
  const int rg = g * 4;
#pragma unroll
  for (int n = 0; n < 4; n++) {
    int col = bcol + wc + n * 16 + ti;
    float bv = (flags & 1) ? bias[col] : 0.0f;
#pragma unroll
    for (int m = 0; m < 4; m++) {
#pragma unroll
      for (int j = 0; j < 4; j++) {
        int row = brow + wr + m * 16 + rg + j;
        float v = acc[m][n][j] + bv;
        if (flags & 2) v = 0.5f * v * (1.0f + erff(v * 0.70710678118654752f));
        size_t off = (size_t)row * ldc + col;
        if (flags & 4) v += C[off];
        C[off] = v;
      }
    }
  }
}

// ------------------------------------------------------------- attention ----
// Flash-style fp32. Layouts (B, N, H*64) row-major, stride 1024. One block per
// (b, h, 64-query tile); streams 64-key tiles with online softmax.
// LDS tiles are 64x64 f32 with XOR swizzle: 4-float block bk of row r stored
// at bk ^ (r>>2)  -> row-strided 16-lane float4 reads are bank-balanced.
__device__ __forceinline__ int ASW(int row, int k) {
  return row * 64 + ((((k >> 2) ^ (row >> 2)) & 15) * 4) + (k & 3);
}

__global__ __launch_bounds__(256) void attn_kernel(
    const float* __restrict__ Q, const float* __restrict__ K,
    const float* __restrict__ V, float* __restrict__ O,
    int Nq, int Nk)
{
  __shared__ __align__(16) float Qs[64 * 64];
  __shared__ __align__(16) float Ks[64 * 64];   // K tile, then reused for P
  __shared__ __align__(16) float Vs[64 * 64];

  const int tid = threadIdx.x;
  const int nqt = Nq >> 6;
  const int qt  = blockIdx.x % nqt;
  const int h   = (blockIdx.x / nqt) & 15;
  const int b   = blockIdx.x / (nqt * 16);

  const float* Qb = Q + ((size_t)b * Nq + qt * 64) * 1024 + h * 64;
  const float* Kb = K + (size_t)b * Nk * 1024 + h * 64;
  const float* Vb = V + (size_t)b * Nk * 1024 + h * 64;

#pragma unroll
  for (int q = 0; q < 4; q++) {
    int s = tid + q * 256;
    int i = s >> 4, d4 = (s & 15) * 4;
    float4 f = *(const float4*)(Qb + (size_t)i * 1024 + d4);
    f.x *= 0.125f; f.y *= 0.125f; f.z *= 0.125f; f.w *= 0.125f;  // SCALE
    *(float4*)&Qs[ASW(i, d4)] = f;
  }

  const int ti = tid >> 4, tj = tid & 15;
  const int i0 = ti * 4, j0 = tj * 4;
  float m_r[4] = {-1e30f, -1e30f, -1e30f, -1e30f};
  float l_r[4] = {0.f, 0.f, 0.f, 0.f};
  float o[4][4] = {};

  for (int kt = 0; kt < Nk; kt += 64) {
    __syncthreads();   // previous iteration's PV fully done
#pragma unroll
    for (int q = 0; q < 4; q++) {
      int s = tid + q * 256;
      int j = s >> 4, d4 = (s & 15) * 4;
      float4 f = *(const float4*)(Kb + (size_t)(kt + j) * 1024 + d4);
      *(float4*)&Ks[ASW(j, d4)] = f;
      float4 gv = *(const float4*)(Vb + (size_t)(kt + j) * 1024 + d4);
      *(float4*)&Vs[ASW(j, d4)] = gv;
    }
    __syncthreads();

    // S = (Q*scale) . K^T, 4x4 per thread
    float s4[4][4] = {};
    for (int k = 0; k < 64; k += 4) {
      float4 qv[4], kv[4];
#pragma unroll
      for (int r = 0; r < 4; r++) qv[r] = *(const float4*)&Qs[ASW(i0 + r, k)];
#pragma unroll
      for (int c = 0; c < 4; c++) kv[c] = *(const float4*)&Ks[ASW(j0 + c, k)];
#pragma unroll
      for (int r = 0; r < 4; r++)
#pragma unroll
        for (int c = 0; c < 4; c++)
          s4[r][c] += qv[r].x * kv[c].x + qv[r].y * kv[c].y +
                      qv[r].z * kv[c].z + qv[r].w * kv[c].w;
    }

    // online softmax; row groups are 16 consecutive lanes (shfl_xor 1/2/4/8)
    float alpha[4], p[4][4];
#pragma unroll
    for (int r = 0; r < 4; r++) {
      float mx = fmaxf(fmaxf(s4[r][0], s4[r][1]), fmaxf(s4[r][2], s4[r][3]));
      mx = fmaxf(mx, __shfl_xor(mx, 1));
      mx = fmaxf(mx, __shfl_xor(mx, 2));
      mx = fmaxf(mx, __shfl_xor(mx, 4));
      mx = fmaxf(mx, __shfl_xor(mx, 8));
      float mn = fmaxf(m_r[r], mx);
      float rs = 0.f;
#pragma unroll
      for (int c = 0; c < 4; c++) { p[r][c] = __expf(s4[r][c] - mn); rs += p[r][c]; }
      rs += __shfl_xor(rs, 1);
      rs += __shfl_xor(rs, 2);
      rs += __shfl_xor(rs, 4);
      rs += __shfl_xor(rs, 8);
      alpha[r] = __expf(m_r[r] - mn);
      l_r[r] = l_r[r] * alpha[r] + rs;
      m_r[r] = mn;
    }

    __syncthreads();   // everyone done reading K tile
#pragma unroll
    for (int r = 0; r < 4; r++) {
      float4 t = make_float4(p[r][0], p[r][1], p[r][2], p[r][3]);
      *(float4*)&Ks[ASW(i0 + r, j0)] = t;   // P into dead K-tile LDS
    }
    __syncthreads();

#pragma unroll
    for (int r = 0; r < 4; r++)
#pragma unroll
      for (int d = 0; d < 4; d++) o[r][d] *= alpha[r];

    // O += P @ V
    for (int j = 0; j < 64; j += 4) {
      float4 pv[4], vv[4];
#pragma unroll
      for (int r = 0; r < 4; r++) pv[r] = *(const float4*)&Ks[ASW(i0 + r, j)];
#pragma unroll
      for (int c = 0; c < 4; c++) vv[c] = *(const float4*)&Vs[ASW(j + c, j0)];
#pragma unroll
      for (int r = 0; r < 4; r++) {
        o[r][0] += pv[r].x * vv[0].x + pv[r].y * vv[1].x + pv[r].z * vv[2].x + pv[r].w * vv[3].x;
        o[r][1] += pv[r].x * vv[0].y + pv[r].y * vv[1].y + pv[r].z * vv[2].y + pv[r].w * vv[3].y;
        o[r][2] += pv[r].x * vv[0].z + pv[r].y * vv[1].z + pv[r].z * vv[2].z + pv[r].w * vv[3].z;
        o[r][3] += pv[r].x * vv[0].w + pv[r].y * vv[1].w + pv[r].z * vv[2].w + pv[r].w * vv[3].w;
      }
    }
  }

#pragma unroll
  for (int r = 0; r < 4; r++) {
    float inv = 1.0f / l_r[r];
    float4 t = make_float4(o[r][0] * inv, o[r][1] * inv, o[r][2] * inv, o[r][3] * inv);
    *(float4*)(O + ((size_t)b * Nq + qt * 64 + i0 + r) * 1024 + h * 64 + j0) = t;
  }
}

// -------------------------------------------------------------- add + LN ----
__global__ __launch_bounds__(256) void add_ln_kernel(
    const float* __restrict__ A, const float* __restrict__ R,
    const float* __restrict__ g, const float* __restrict__ be,
    float* __restrict__ out)
{
  const int row = blockIdx.x;
  const size_t base = (size_t)row * 1024 + threadIdx.x * 4;
  float4 a = *(const float4*)(A + base);
  float4 r = *(const float4*)(R + base);
  float v0 = a.x + r.x, v1 = a.y + r.y, v2 = a.z + r.z, v3 = a.w + r.w;
  float s  = v0 + v1 + v2 + v3;
  float ss = v0 * v0 + v1 * v1 + v2 * v2 + v3 * v3;
#pragma unroll
  for (int m = 1; m < 64; m <<= 1) { s += __shfl_xor(s, m); ss += __shfl_xor(ss, m); }
  __shared__ float red[8];
  const int wid = threadIdx.x >> 6;
  if ((threadIdx.x & 63) == 0) { red[wid] = s; red[4 + wid] = ss; }
  __syncthreads();
  s  = red[0] + red[1] + red[2] + red[3];
  ss = red[4] + red[5] + red[6] + red[7];
  float mean = s * (1.0f / 1024.0f);
  float var  = ss * (1.0f / 1024.0f) - mean * mean;
  float inv  = 1.0f / sqrtf(var + 1e-5f);
  float4 gg = *(const float4*)(g + threadIdx.x * 4);
  float4 bb = *(const float4*)(be + threadIdx.x * 4);
  float4 ov;
  ov.x = (v0 - mean) * inv * gg.x + bb.x;
  ov.y = (v1 - mean) * inv * gg.y + bb.y;
  ov.z = (v2 - mean) * inv * gg.z + bb.z;
  ov.w = (v3 - mean) * inv * gg.w + bb.w;
  *(float4*)(out + base) = ov;
}

// ---------------------------------------------------------------- launch ----
extern "C" void kernel_launch(void* const* d_in, const int* in_sizes, int n_in,
                              void* d_out, int out_size, void* d_ws, size_t ws_size,
                              hipStream_t stream)
{
  const float* x    = (const float*)d_in[0];
  const float* p    = (const float*)d_in[1];
  const float* pq_w = (const float*)d_in[2];
  const float* pk_w = (const float*)d_in[3];
  const float* pv_w = (const float*)d_in[4];
  const float* po_w = (const float*)d_in[5];
  const float* po_b = (const float*)d_in[6];
  const float* xq_w = (const float*)d_in[7];
  const float* xk_w = (const float*)d_in[8];
  const float* xv_w = (const float*)d_in[9];
  const float* xo_w = (const float*)d_in[10];
  const float* xo_b = (const float*)d_in[11];
  const float* pn_g = (const float*)d_in[12];
  const float* pn_b = (const float*)d_in[13];
  const float* xn_g = (const float*)d_in[14];
  const float* xn_b = (const float*)d_in[15];
  const float* w1   = (const float*)d_in[16];
  const float* b1   = (const float*)d_in[17];
  const float* w2   = (const float*)d_in[18];
  const float* b2   = (const float*)d_in[19];
  const float* fn_g = (const float*)d_in[20];
  const float* fn_b = (const float*)d_in[21];

  float* out_x = (float*)d_out;            // (4,4096,1024)
  float* out_p = out_x + 16777216;         // (4,256,1024)

  float* ws = (float*)d_ws;
  float* W0 = ws;                          // 16M floats
  float* W1 = ws + 16777216;               // 16M floats
  float* S0 = ws + 33554432;               // 1M floats
  float* S1 = S0 + 1048576;
  float* S2 = S1 + 1048576;
  float* S3 = S2 + 1048576;

  const dim3 blk(256, 1, 1);
#define GEMM(A_, lda_, B_, ldb_, bias_, C_, ldc_, M_, N_, K_, fl_)              \
  gemm_kernel<<<dim3((N_) / 128, (M_) / 128, 1), blk, 0, stream>>>(             \
      A_, lda_, B_, ldb_, bias_, C_, ldc_, K_, fl_)

  // ---- p attends to x ----
  GEMM(p, 1024, pq_w, 1024, nullptr, S0, 1024, 1024, 1024, 1024, 0);    // Qp
  GEMM(x, 1024, pk_w, 1024, nullptr, W0, 1024, 16384, 1024, 1024, 0);   // Kx
  GEMM(x, 1024, pv_w, 1024, nullptr, W1, 1024, 16384, 1024, 1024, 0);   // Vx
  attn_kernel<<<dim3(4 * 16 * (256 / 64)), blk, 0, stream>>>(S0, W0, W1, S1, 256, 4096);
  GEMM(S1, 1024, po_w, 1024, po_b, S2, 1024, 1024, 1024, 1024, 1);      // p_att
  add_ln_kernel<<<dim3(1024), blk, 0, stream>>>(S2, p, pn_g, pn_b, out_p);  // p_new

  // ---- x attends to p_att ----
  GEMM(x, 1024, xq_w, 1024, nullptr, W0, 1024, 16384, 1024, 1024, 0);   // Qx
  GEMM(S2, 1024, xk_w, 1024, nullptr, S0, 1024, 1024, 1024, 1024, 0);   // Kp
  GEMM(S2, 1024, xv_w, 1024, nullptr, S3, 1024, 1024, 1024, 1024, 0);   // Vp
  attn_kernel<<<dim3(4 * 16 * (4096 / 64)), blk, 0, stream>>>(W0, S0, S3, W1, 4096, 256);
  GEMM(W1, 1024, xo_w, 1024, xo_b, W0, 1024, 16384, 1024, 1024, 1);     // x_att
  add_ln_kernel<<<dim3(16384), blk, 0, stream>>>(W0, x, xn_g, xn_b, out_x);  // x1

  // ---- MLP, split along hidden dim into 4 passes of 1024 ----
  for (int nt = 0; nt < 4; nt++) {
    GEMM(out_x, 1024, w1 + nt * 1024, 4096, b1 + nt * 1024, W0, 1024,
         16384, 1024, 1024, 1 | 2);                                      // gelu(x1@w1+b1)
    GEMM(W0, 1024, w2 + (size_t)nt * 1024 * 1024, 1024,
         (nt == 0) ? b2 : nullptr, W1, 1024, 16384, 1024, 1024,
         (nt == 0) ? 1 : 4);                                             // x_ff (+=)
  }
  add_ln_kernel<<<dim3(16384), blk, 0, stream>>>(W1, out_x, fn_g, fn_b, out_x);
#undef GEMM
}

// Round 7
// 2287.064 us; speedup vs baseline: 2.4220x; 1.2488x over previous
//
#include <hip/hip_runtime.h>

// ----------------------------------------------------------------------------
// Luna cross-attention block, fp32 in/out.
// GEMMs: bf16x3 split-precision MFMA (unchanged from round 6 — passing).
// Attention: NOW MFMA flash kernel. QK^T x3 (Qh/Ql x Kh/Kl), softmax on C
// fragments (m89 layout), P->bf16 via LDS round-trip (wave-local rows),
// PV with P,V hi-only. All fragment flows are isomorphs of the r6 GEMM.
//
// Workspace layout (floats), total 37,748,736 floats = 151 MB (r1-proven).
// ----------------------------------------------------------------------------

typedef short bf16x8 __attribute__((ext_vector_type(8)));
typedef float f32x4 __attribute__((ext_vector_type(4)));
typedef unsigned int u32x2 __attribute__((ext_vector_type(2)));
typedef unsigned int u32x4v __attribute__((ext_vector_type(4)));

__device__ __forceinline__ unsigned cvt_pk_bf16(float a, float b) {
  unsigned r;
  asm("v_cvt_pk_bf16_f32 %0, %1, %2" : "=v"(r) : "v"(a), "v"(b));
  return r;   // low 16 = bf16(a), high 16 = bf16(b)
}
__device__ __forceinline__ bf16x8 mk8(u32x2 a, u32x2 b) {
  u32x4v t; t.x = a.x; t.y = a.y; t.z = b.x; t.w = b.y;
  return __builtin_bit_cast(bf16x8, t);
}

// ---------------------------------------------------------------- GEMM ------
// (byte-identical to round 6 — passing at ~150 us/big dispatch)
#define AST 36
#define SEL_LO 0x05040100u
#define SEL_HI 0x07060302u

__global__ __launch_bounds__(256, 2) void gemm_kernel(
    const float* __restrict__ A, int lda,
    const float* __restrict__ Bw, int ldb,
    const float* __restrict__ bias,
    float* __restrict__ C, int ldc,
    int K, int flags)
{
  __shared__ __align__(16) unsigned short Ah[128 * AST];
  __shared__ __align__(16) unsigned short Al[128 * AST];
  __shared__ __align__(16) unsigned short Bh[128 * AST];
  __shared__ __align__(16) unsigned short Bl[128 * AST];

  const int tid = threadIdx.x;
  const int bid   = blockIdx.y * gridDim.x + blockIdx.x;
  const int chunk = (gridDim.x * gridDim.y) >> 3;
  const int lg    = (bid & 7) * chunk + (bid >> 3);
  const int bcol  = (lg % gridDim.x) * 128;
  const int brow  = (lg / gridDim.x) * 128;

  const int lane = tid & 63;
  const int w    = tid >> 6;
  const int wr   = (w >> 1) * 64;
  const int wc   = (w & 1) * 64;
  const int ti   = lane & 15;
  const int g    = lane >> 4;

  const int arow = tid >> 3;
  const int ac4  = (tid & 7) * 4;
  const int K0   = (tid >> 5) * 4;
  const int n4   = (tid & 31) * 4;
  int bwa[4];
#pragma unroll
  for (int i = 0; i < 4; i++)
    bwa[i] = (n4 + i) * AST + ((K0 + 4 * (((n4 + i) >> 2) & 7)) & 31);
  int brofs[4], brbase[4];
#pragma unroll
  for (int nb = 0; nb < 4; nb++) {
    int n = wc + nb * 16 + ti;
    brbase[nb] = n * AST;
    brofs[nb]  = (4 * g + 4 * ((n >> 2) & 7)) & 31;
  }

  f32x4 acc[4][4];
#pragma unroll
  for (int m = 0; m < 4; m++)
#pragma unroll
    for (int n = 0; n < 4; n++) acc[m][n] = (f32x4){0.f, 0.f, 0.f, 0.f};

  float4 fA[4], fB[4];
#pragma unroll
  for (int q = 0; q < 4; q++) {
    fA[q] = *(const float4*)(A + (size_t)(brow + arow + 32 * q) * lda + ac4);
    fB[q] = *(const float4*)(Bw + (size_t)(K0 + q) * ldb + bcol + n4);
  }

  for (int kb = 0; kb < K; kb += 32) {
    __syncthreads();
#pragma unroll
    for (int q = 0; q < 4; q++) {
      float4 f = fA[q];
      unsigned h01 = cvt_pk_bf16(f.x, f.y);
      unsigned h23 = cvt_pk_bf16(f.z, f.w);
      unsigned l01 = cvt_pk_bf16(f.x - __uint_as_float(h01 << 16),
                                 f.y - __uint_as_float(h01 & 0xffff0000u));
      unsigned l23 = cvt_pk_bf16(f.z - __uint_as_float(h23 << 16),
                                 f.w - __uint_as_float(h23 & 0xffff0000u));
      int el = (arow + 32 * q) * AST + ac4;
      *(uint2*)&Ah[el] = make_uint2(h01, h23);
      *(uint2*)&Al[el] = make_uint2(l01, l23);
    }
    {
      unsigned h01[4], h23[4], l01[4], l23[4];
#pragma unroll
      for (int q = 0; q < 4; q++) {
        float4 f = fB[q];
        h01[q] = cvt_pk_bf16(f.x, f.y);
        h23[q] = cvt_pk_bf16(f.z, f.w);
        l01[q] = cvt_pk_bf16(f.x - __uint_as_float(h01[q] << 16),
                             f.y - __uint_as_float(h01[q] & 0xffff0000u));
        l23[q] = cvt_pk_bf16(f.z - __uint_as_float(h23[q] << 16),
                             f.w - __uint_as_float(h23[q] & 0xffff0000u));
      }
      uint2 vh[4], vl[4];
      vh[0] = make_uint2(__builtin_amdgcn_perm(h01[1], h01[0], SEL_LO),
                         __builtin_amdgcn_perm(h01[3], h01[2], SEL_LO));
      vh[1] = make_uint2(__builtin_amdgcn_perm(h01[1], h01[0], SEL_HI),
                         __builtin_amdgcn_perm(h01[3], h01[2], SEL_HI));
      vh[2] = make_uint2(__builtin_amdgcn_perm(h23[1], h23[0], SEL_LO),
                         __builtin_amdgcn_perm(h23[3], h23[2], SEL_LO));
      vh[3] = make_uint2(__builtin_amdgcn_perm(h23[1], h23[0], SEL_HI),
                         __builtin_amdgcn_perm(h23[3], h23[2], SEL_HI));
      vl[0] = make_uint2(__builtin_amdgcn_perm(l01[1], l01[0], SEL_LO),
                         __builtin_amdgcn_perm(l01[3], l01[2], SEL_LO));
      vl[1] = make_uint2(__builtin_amdgcn_perm(l01[1], l01[0], SEL_HI),
                         __builtin_amdgcn_perm(l01[3], l01[2], SEL_HI));
      vl[2] = make_uint2(__builtin_amdgcn_perm(l23[1], l23[0], SEL_LO),
                         __builtin_amdgcn_perm(l23[3], l23[2], SEL_LO));
      vl[3] = make_uint2(__builtin_amdgcn_perm(l23[1], l23[0], SEL_HI),
                         __builtin_amdgcn_perm(l23[3], l23[2], SEL_HI));
#pragma unroll
      for (int i = 0; i < 4; i++) {
        *(uint2*)&Bh[bwa[i]] = vh[i];
        *(uint2*)&Bl[bwa[i]] = vl[i];
      }
    }
    __syncthreads();

    if (kb + 32 < K) {
#pragma unroll
      for (int q = 0; q < 4; q++) {
        fA[q] = *(const float4*)(A + (size_t)(brow + arow + 32 * q) * lda + kb + 32 + ac4);
        fB[q] = *(const float4*)(Bw + (size_t)(kb + 32 + K0 + q) * ldb + bcol + n4);
      }
    }

    u32x2 fa_h[4][2], fa_l[4][2], fb_h[4][2], fb_l[4][2];
#pragma unroll
    for (int m = 0; m < 4; m++) {
      int e0 = (wr + m * 16 + ti) * AST + 4 * g;
      fa_h[m][0] = *(const u32x2*)&Ah[e0];
      fa_h[m][1] = *(const u32x2*)&Ah[e0 + 16];
      fa_l[m][0] = *(const u32x2*)&Al[e0];
      fa_l[m][1] = *(const u32x2*)&Al[e0 + 16];
    }
#pragma unroll
    for (int nb = 0; nb < 4; nb++) {
      int e0 = brbase[nb] + brofs[nb];
      int e1 = brbase[nb] + (brofs[nb] ^ 16);
      fb_h[nb][0] = *(const u32x2*)&Bh[e0];
      fb_h[nb][1] = *(const u32x2*)&Bh[e1];
      fb_l[nb][0] = *(const u32x2*)&Bl[e0];
      fb_l[nb][1] = *(const u32x2*)&Bl[e1];
    }

#pragma unroll
    for (int m = 0; m < 4; m++) {
      bf16x8 ah = mk8(fa_h[m][0], fa_h[m][1]);
      bf16x8 al = mk8(fa_l[m][0], fa_l[m][1]);
#pragma unroll
      for (int n = 0; n < 4; n++) {
        bf16x8 bh = mk8(fb_h[n][0], fb_h[n][1]);
        bf16x8 bl = mk8(fb_l[n][0], fb_l[n][1]);
        acc[m][n] = __builtin_amdgcn_mfma_f32_16x16x32_bf16(ah, bh, acc[m][n], 0, 0, 0);
        acc[m][n] = __builtin_amdgcn_mfma_f32_16x16x32_bf16(al, bh, acc[m][n], 0, 0, 0);
        acc[m][n] = __builtin_amdgcn_mfma_f32_16x16x32_bf16(ah, bl, acc[m][n], 0, 0, 0);
      }
    }
  }

  const int rg = g * 4;
#pragma unroll
  for (int n = 0; n < 4; n++) {
    int col = bcol + wc + n * 16 + ti;
    float bv = (flags & 1) ? bias[col] : 0.0f;
#pragma unroll
    for (int m = 0; m < 4; m++) {
#pragma unroll
      for (int j = 0; j < 4; j++) {
        int row = brow + wr + m * 16 + rg + j;
        float v = acc[m][n][j] + bv;
        if (flags & 2) v = 0.5f * v * (1.0f + erff(v * 0.70710678118654752f));
        size_t off = (size_t)row * ldc + col;
        if (flags & 4) v += C[off];
        C[off] = v;
      }
    }
  }
}

// ------------------------------------------------------------- attention ----
// MFMA flash attention. One block = 64 q-rows (4 waves x 16 rows), streams
// 64-key tiles. Layouts (halfwords, stride 72/row):
//   Qh/Ql, Kh/Kl: elem (row, d)  at row*72 + ((d  + 4*(row&7)) & 63)
//   Vh (V^T)    : elem (d, key)  at d*72   + ((key + 4*((d>>2)&7)) & 63)
//   P (in Qh)   : elem (q, key)  at q*72   + key            (plain; rows are
//                 wave-local: written and read by the same wave -> no barrier)
// QK^T: A=Q(hi/lo) B=K(hi/lo, natural layout IS k-major) x3. PV: A=P(hi)
// B=V^T(hi). C/D layout m89: col=lane&15, row=4*(lane>>4)+j.
__global__ __launch_bounds__(256) void attn_kernel(
    const float* __restrict__ Q, const float* __restrict__ K,
    const float* __restrict__ V, float* __restrict__ O,
    int Nq, int Nk)
{
  __shared__ __align__(16) unsigned short Qh[64 * 72];   // then P
  __shared__ __align__(16) unsigned short Ql[64 * 72];
  __shared__ __align__(16) unsigned short Kh[64 * 72];
  __shared__ __align__(16) unsigned short Kl[64 * 72];
  __shared__ __align__(16) unsigned short Vh[64 * 72];

  const int tid = threadIdx.x;
  const int nqt = Nq >> 6;
  const int qt  = blockIdx.x % nqt;
  const int h   = (blockIdx.x / nqt) & 15;
  const int b   = blockIdx.x / (nqt * 16);

  const float* Qb = Q + ((size_t)b * Nq + qt * 64) * 1024 + h * 64;
  const float* Kb = K + (size_t)b * Nk * 1024 + h * 64;
  const float* Vb = V + (size_t)b * Nk * 1024 + h * 64;

  const int lane  = tid & 63;
  const int w     = tid >> 6;
  const int ti    = lane & 15;
  const int g     = lane >> 4;
  const int rot16 = 4 * (ti & 7);

  // staging maps (thread-constant)
  const int krow = tid >> 2;            // 0..63
  const int kd   = (tid & 3) * 16;      // d base, 4 float4
  const int krot = 4 * (krow & 7);
  const int vkq  = (tid >> 4) * 4;      // key-quad base
  const int vd4  = (tid & 15) * 4;      // d-row base
  const int vcol = (vkq + 4 * ((tid & 15) & 7)) & 63;
  int rotv[4];
#pragma unroll
  for (int df = 0; df < 4; df++) rotv[df] = 4 * ((4 * df + (ti >> 2)) & 7);

  // ---- stage Q (scale folded, hi/lo) ----
#pragma unroll
  for (int i = 0; i < 4; i++) {
    float4 f = *(const float4*)(Qb + (size_t)krow * 1024 + kd + 4 * i);
    f.x *= 0.125f; f.y *= 0.125f; f.z *= 0.125f; f.w *= 0.125f;
    unsigned h01 = cvt_pk_bf16(f.x, f.y);
    unsigned h23 = cvt_pk_bf16(f.z, f.w);
    unsigned l01 = cvt_pk_bf16(f.x - __uint_as_float(h01 << 16),
                               f.y - __uint_as_float(h01 & 0xffff0000u));
    unsigned l23 = cvt_pk_bf16(f.z - __uint_as_float(h23 << 16),
                               f.w - __uint_as_float(h23 & 0xffff0000u));
    int el = krow * 72 + ((kd + 4 * i + krot) & 63);
    *(uint2*)&Qh[el] = make_uint2(h01, h23);
    *(uint2*)&Ql[el] = make_uint2(l01, l23);
  }
  __syncthreads();

  // ---- hoist Q fragments (rows 16w+ti); Qh is dead (becomes P) after this --
  bf16x8 qh8[2], ql8[2];
  {
    int qrb = (16 * w + ti) * 72;
#pragma unroll
    for (int kc = 0; kc < 2; kc++) {
      int c0 = (kc * 32 + 4 * g + rot16) & 63;
      int c1 = (kc * 32 + 4 * g + 16 + rot16) & 63;
      qh8[kc] = mk8(*(const u32x2*)&Qh[qrb + c0], *(const u32x2*)&Qh[qrb + c1]);
      ql8[kc] = mk8(*(const u32x2*)&Ql[qrb + c0], *(const u32x2*)&Ql[qrb + c1]);
    }
  }

  f32x4 acc_o[4];
#pragma unroll
  for (int df = 0; df < 4; df++) acc_o[df] = (f32x4){0.f, 0.f, 0.f, 0.f};
  float m_r[4] = {-1e30f, -1e30f, -1e30f, -1e30f};
  float l_r[4] = {0.f, 0.f, 0.f, 0.f};

  for (int kt = 0; kt < Nk; kt += 64) {
    __syncthreads();   // prior tile's PV reads of Kh/Kl/Vh complete
    // ---- stage K (hi/lo, natural row-major = B k-major for QK^T) ----
#pragma unroll
    for (int i = 0; i < 4; i++) {
      float4 f = *(const float4*)(Kb + (size_t)(kt + krow) * 1024 + kd + 4 * i);
      unsigned h01 = cvt_pk_bf16(f.x, f.y);
      unsigned h23 = cvt_pk_bf16(f.z, f.w);
      unsigned l01 = cvt_pk_bf16(f.x - __uint_as_float(h01 << 16),
                                 f.y - __uint_as_float(h01 & 0xffff0000u));
      unsigned l23 = cvt_pk_bf16(f.z - __uint_as_float(h23 << 16),
                                 f.w - __uint_as_float(h23 & 0xffff0000u));
      int el = krow * 72 + ((kd + 4 * i + krot) & 63);
      *(uint2*)&Kh[el] = make_uint2(h01, h23);
      *(uint2*)&Kl[el] = make_uint2(l01, l23);
    }
    // ---- stage V^T (hi only) via v_perm k-packing (r6-GEMM-proven path) ----
    {
      unsigned h01[4], h23[4];
#pragma unroll
      for (int q = 0; q < 4; q++) {
        float4 f = *(const float4*)(Vb + (size_t)(kt + vkq + q) * 1024 + vd4);
        h01[q] = cvt_pk_bf16(f.x, f.y);
        h23[q] = cvt_pk_bf16(f.z, f.w);
      }
      uint2 t0 = make_uint2(__builtin_amdgcn_perm(h01[1], h01[0], SEL_LO),
                            __builtin_amdgcn_perm(h01[3], h01[2], SEL_LO));
      uint2 t1 = make_uint2(__builtin_amdgcn_perm(h01[1], h01[0], SEL_HI),
                            __builtin_amdgcn_perm(h01[3], h01[2], SEL_HI));
      uint2 t2 = make_uint2(__builtin_amdgcn_perm(h23[1], h23[0], SEL_LO),
                            __builtin_amdgcn_perm(h23[3], h23[2], SEL_LO));
      uint2 t3 = make_uint2(__builtin_amdgcn_perm(h23[1], h23[0], SEL_HI),
                            __builtin_amdgcn_perm(h23[3], h23[2], SEL_HI));
      *(uint2*)&Vh[(vd4 + 0) * 72 + vcol] = t0;
      *(uint2*)&Vh[(vd4 + 1) * 72 + vcol] = t1;
      *(uint2*)&Vh[(vd4 + 2) * 72 + vcol] = t2;
      *(uint2*)&Vh[(vd4 + 3) * 72 + vcol] = t3;
    }
    __syncthreads();

    // ---- QK^T (x3): S[q=16w+4g+j][key=16nf+ti'] ----
    f32x4 sc[4];
#pragma unroll
    for (int nf = 0; nf < 4; nf++) sc[nf] = (f32x4){0.f, 0.f, 0.f, 0.f};
#pragma unroll
    for (int nf = 0; nf < 4; nf++) {
      int rb = (16 * nf + ti) * 72;
#pragma unroll
      for (int kc = 0; kc < 2; kc++) {
        int c0 = (kc * 32 + 4 * g + rot16) & 63;
        int c1 = (kc * 32 + 4 * g + 16 + rot16) & 63;
        bf16x8 bh = mk8(*(const u32x2*)&Kh[rb + c0], *(const u32x2*)&Kh[rb + c1]);
        bf16x8 bl = mk8(*(const u32x2*)&Kl[rb + c0], *(const u32x2*)&Kl[rb + c1]);
        sc[nf] = __builtin_amdgcn_mfma_f32_16x16x32_bf16(qh8[kc], bh, sc[nf], 0, 0, 0);
        sc[nf] = __builtin_amdgcn_mfma_f32_16x16x32_bf16(ql8[kc], bh, sc[nf], 0, 0, 0);
        sc[nf] = __builtin_amdgcn_mfma_f32_16x16x32_bf16(qh8[kc], bl, sc[nf], 0, 0, 0);
      }
    }

    // ---- online softmax; row j lives in the 16-lane ti-group ----
    float pr[4][4];
#pragma unroll
    for (int j = 0; j < 4; j++) {
      float mx = fmaxf(fmaxf(sc[0][j], sc[1][j]), fmaxf(sc[2][j], sc[3][j]));
      mx = fmaxf(mx, __shfl_xor(mx, 1));
      mx = fmaxf(mx, __shfl_xor(mx, 2));
      mx = fmaxf(mx, __shfl_xor(mx, 4));
      mx = fmaxf(mx, __shfl_xor(mx, 8));
      float mn = fmaxf(m_r[j], mx);
      float al = __expf(m_r[j] - mn);
      float rs = 0.f;
#pragma unroll
      for (int nf = 0; nf < 4; nf++) { pr[nf][j] = __expf(sc[nf][j] - mn); rs += pr[nf][j]; }
      rs += __shfl_xor(rs, 1);
      rs += __shfl_xor(rs, 2);
      rs += __shfl_xor(rs, 4);
      rs += __shfl_xor(rs, 8);
      l_r[j] = l_r[j] * al + rs;
      m_r[j] = mn;
#pragma unroll
      for (int df = 0; df < 4; df++) acc_o[df][j] *= al;
    }

    // ---- P -> bf16 into Qh (rows 16w+4g+j: wave-local, no barrier) ----
#pragma unroll
    for (int nf = 0; nf < 4; nf++)
#pragma unroll
      for (int j = 0; j < 4; j++)
        Qh[(16 * w + 4 * g + j) * 72 + 16 * nf + ti] =
            (unsigned short)cvt_pk_bf16(pr[nf][j], pr[nf][j]);

    // ---- PV: O[q][d=16df+ti'] += P[q][key] V[key][d] ----
#pragma unroll
    for (int kc = 0; kc < 2; kc++) {
      int ab = (16 * w + ti) * 72 + kc * 32 + 4 * g;
      bf16x8 pa = mk8(*(const u32x2*)&Qh[ab], *(const u32x2*)&Qh[ab + 16]);
#pragma unroll
      for (int df = 0; df < 4; df++) {
        int rb = (16 * df + ti) * 72;
        int c0 = (kc * 32 + 4 * g + rotv[df]) & 63;
        int c1 = (kc * 32 + 4 * g + 16 + rotv[df]) & 63;
        bf16x8 vb = mk8(*(const u32x2*)&Vh[rb + c0], *(const u32x2*)&Vh[rb + c1]);
        acc_o[df] = __builtin_amdgcn_mfma_f32_16x16x32_bf16(pa, vb, acc_o[df], 0, 0, 0);
      }
    }
  }

  // ---- epilogue: O / l ----
  float inv[4];
#pragma unroll
  for (int j = 0; j < 4; j++) inv[j] = 1.0f / l_r[j];
#pragma unroll
  for (int df = 0; df < 4; df++)
#pragma unroll
    for (int j = 0; j < 4; j++)
      O[((size_t)b * Nq + qt * 64 + 16 * w + 4 * g + j) * 1024 + h * 64 + 16 * df + ti] =
          acc_o[df][j] * inv[j];
}

// -------------------------------------------------------------- add + LN ----
__global__ __launch_bounds__(256) void add_ln_kernel(
    const float* __restrict__ A, const float* __restrict__ R,
    const float* __restrict__ g, const float* __restrict__ be,
    float* __restrict__ out)
{
  const int row = blockIdx.x;
  const size_t base = (size_t)row * 1024 + threadIdx.x * 4;
  float4 a = *(const float4*)(A + base);
  float4 r = *(const float4*)(R + base);
  float v0 = a.x + r.x, v1 = a.y + r.y, v2 = a.z + r.z, v3 = a.w + r.w;
  float s  = v0 + v1 + v2 + v3;
  float ss = v0 * v0 + v1 * v1 + v2 * v2 + v3 * v3;
#pragma unroll
  for (int m = 1; m < 64; m <<= 1) { s += __shfl_xor(s, m); ss += __shfl_xor(ss, m); }
  __shared__ float red[8];
  const int wid = threadIdx.x >> 6;
  if ((threadIdx.x & 63) == 0) { red[wid] = s; red[4 + wid] = ss; }
  __syncthreads();
  s  = red[0] + red[1] + red[2] + red[3];
  ss = red[4] + red[5] + red[6] + red[7];
  float mean = s * (1.0f / 1024.0f);
  float var  = ss * (1.0f / 1024.0f) - mean * mean;
  float inv  = 1.0f / sqrtf(var + 1e-5f);
  float4 gg = *(const float4*)(g + threadIdx.x * 4);
  float4 bb = *(const float4*)(be + threadIdx.x * 4);
  float4 ov;
  ov.x = (v0 - mean) * inv * gg.x + bb.x;
  ov.y = (v1 - mean) * inv * gg.y + bb.y;
  ov.z = (v2 - mean) * inv * gg.z + bb.z;
  ov.w = (v3 - mean) * inv * gg.w + bb.w;
  *(float4*)(out + base) = ov;
}

// ---------------------------------------------------------------- launch ----
extern "C" void kernel_launch(void* const* d_in, const int* in_sizes, int n_in,
                              void* d_out, int out_size, void* d_ws, size_t ws_size,
                              hipStream_t stream)
{
  const float* x    = (const float*)d_in[0];
  const float* p    = (const float*)d_in[1];
  const float* pq_w = (const float*)d_in[2];
  const float* pk_w = (const float*)d_in[3];
  const float* pv_w = (const float*)d_in[4];
  const float* po_w = (const float*)d_in[5];
  const float* po_b = (const float*)d_in[6];
  const float* xq_w = (const float*)d_in[7];
  const float* xk_w = (const float*)d_in[8];
  const float* xv_w = (const float*)d_in[9];
  const float* xo_w = (const float*)d_in[10];
  const float* xo_b = (const float*)d_in[11];
  const float* pn_g = (const float*)d_in[12];
  const float* pn_b = (const float*)d_in[13];
  const float* xn_g = (const float*)d_in[14];
  const float* xn_b = (const float*)d_in[15];
  const float* w1   = (const float*)d_in[16];
  const float* b1   = (const float*)d_in[17];
  const float* w2   = (const float*)d_in[18];
  const float* b2   = (const float*)d_in[19];
  const float* fn_g = (const float*)d_in[20];
  const float* fn_b = (const float*)d_in[21];

  float* out_x = (float*)d_out;            // (4,4096,1024)
  float* out_p = out_x + 16777216;         // (4,256,1024)

  float* ws = (float*)d_ws;
  float* W0 = ws;                          // 16M floats
  float* W1 = ws + 16777216;               // 16M floats
  float* S0 = ws + 33554432;               // 1M floats
  float* S1 = S0 + 1048576;
  float* S2 = S1 + 1048576;
  float* S3 = S2 + 1048576;

  const dim3 blk(256, 1, 1);
#define GEMM(A_, lda_, B_, ldb_, bias_, C_, ldc_, M_, N_, K_, fl_)              \
  gemm_kernel<<<dim3((N_) / 128, (M_) / 128, 1), blk, 0, stream>>>(             \
      A_, lda_, B_, ldb_, bias_, C_, ldc_, K_, fl_)

  // ---- p attends to x ----
  GEMM(p, 1024, pq_w, 1024, nullptr, S0, 1024, 1024, 1024, 1024, 0);    // Qp
  GEMM(x, 1024, pk_w, 1024, nullptr, W0, 1024, 16384, 1024, 1024, 0);   // Kx
  GEMM(x, 1024, pv_w, 1024, nullptr, W1, 1024, 16384, 1024, 1024, 0);   // Vx
  attn_kernel<<<dim3(4 * 16 * (256 / 64)), blk, 0, stream>>>(S0, W0, W1, S1, 256, 4096);
  GEMM(S1, 1024, po_w, 1024, po_b, S2, 1024, 1024, 1024, 1024, 1);      // p_att
  add_ln_kernel<<<dim3(1024), blk, 0, stream>>>(S2, p, pn_g, pn_b, out_p);  // p_new

  // ---- x attends to p_att ----
  GEMM(x, 1024, xq_w, 1024, nullptr, W0, 1024, 16384, 1024, 1024, 0);   // Qx
  GEMM(S2, 1024, xk_w, 1024, nullptr, S0, 1024, 1024, 1024, 1024, 0);   // Kp
  GEMM(S2, 1024, xv_w, 1024, nullptr, S3, 1024, 1024, 1024, 1024, 0);   // Vp
  attn_kernel<<<dim3(4 * 16 * (4096 / 64)), blk, 0, stream>>>(W0, S0, S3, W1, 4096, 256);
  GEMM(W1, 1024, xo_w, 1024, xo_b, W0, 1024, 16384, 1024, 1024, 1);     // x_att
  add_ln_kernel<<<dim3(16384), blk, 0, stream>>>(W0, x, xn_g, xn_b, out_x);  // x1

  // ---- MLP, split along hidden dim into 4 passes of 1024 ----
  for (int nt = 0; nt < 4; nt++) {
    GEMM(out_x, 1024, w1 + nt * 1024, 4096, b1 + nt * 1024, W0, 1024,
         16384, 1024, 1024, 1 | 2);                                      // gelu(x1@w1+b1)
    GEMM(W0, 1024, w2 + (size_t)nt * 1024 * 1024, 1024,
         (nt == 0) ? b2 : nullptr, W1, 1024, 16384, 1024, 1024,
         (nt == 0) ? 1 : 4);                                             // x_ff (+=)
  }
  add_ln_kernel<<<dim3(16384), blk, 0, stream>>>(W1, out_x, fn_g, fn_b, out_x);
#undef GEMM
}